// Round 1
// baseline (393.987 us; speedup 1.0000x reference)
//
#include <hip/hip_runtime.h>
#include <stdint.h>

#define D     512
#define NSUP  5000   // 1000 classes * 5 shots
#define NQRY  5000
#define MEAN_BLOCKS 100
#define ROWS_PER_MEAN_BLOCK 50

// ---------------- ws layout (bytes) ----------------
// s_n     : [5000][512] f32   @ 0            (10,485,760)
// q_n     : [5000][512] f32   @ 10,485,760   (10,485,760)
// partial : [100][512]  f32   @ 20,971,520   (204,800)
// mean    : [512]       f32   @ 21,176,320   (2,048)
// keys    : [5000]      u64   @ 21,178,368   (40,000)
#define OFF_SN      0
#define OFF_QN      10485760
#define OFF_PARTIAL 20971520
#define OFF_MEAN    21176320
#define OFF_KEYS    21178368

__device__ __forceinline__ unsigned long long pack_key(float v, int sidx) {
    unsigned u = __float_as_uint(v);
    u = (u & 0x80000000u) ? ~u : (u | 0x80000000u);   // monotone float->uint
    // tie-break: smaller support index must win => larger low word
    return ((unsigned long long)u << 32) | (unsigned)(0xFFFFFFFFu - (unsigned)sidx);
}

// K1: partial column sums of support over row chunks (deterministic)
__global__ void k_partial_mean(const float* __restrict__ sup, float* __restrict__ partial) {
    const int col = threadIdx.x;           // 512
    const int b   = blockIdx.x;            // 100
    const int r0  = b * ROWS_PER_MEAN_BLOCK;
    float acc = 0.0f;
    for (int r = 0; r < ROWS_PER_MEAN_BLOCK; ++r)
        acc += sup[(size_t)(r0 + r) * D + col];
    partial[b * D + col] = acc;
}

// K2: finish mean, zero the key array
__global__ void k_mean_init(const float* __restrict__ partial, float* __restrict__ mean,
                            unsigned long long* __restrict__ keys) {
    const int col = threadIdx.x;           // 512
    float acc = 0.0f;
    for (int b = 0; b < MEAN_BLOCKS; ++b) acc += partial[b * D + col];
    mean[col] = acc * (1.0f / (float)NSUP);
    for (int i = col; i < NSUP; i += 512) keys[i] = 0ull;
}

// K3: mean-center + L2-normalize each support/query row. grid = NSUP+NQRY, block = 128
__global__ void k_normalize(const float* __restrict__ sup, const float* __restrict__ qry,
                            const float* __restrict__ mean,
                            float* __restrict__ s_n, float* __restrict__ q_n) {
    const int b = blockIdx.x;
    const float* src;
    float* dst;
    if (b < NSUP) { src = sup + (size_t)b * D;          dst = s_n + (size_t)b * D; }
    else          { src = qry + (size_t)(b - NSUP) * D; dst = q_n + (size_t)(b - NSUP) * D; }
    const int t = threadIdx.x;             // 128 threads, 4 floats each
    float4 v = *(const float4*)(src + t * 4);
    float4 m = *(const float4*)(mean + t * 4);
    v.x -= m.x; v.y -= m.y; v.z -= m.z; v.w -= m.w;
    float ss = v.x * v.x + v.y * v.y + v.z * v.z + v.w * v.w;
    #pragma unroll
    for (int off = 32; off > 0; off >>= 1) ss += __shfl_down(ss, off, 64);
    __shared__ float red[2];
    if ((t & 63) == 0) red[t >> 6] = ss;
    __syncthreads();
    const float rn = 1.0f / sqrtf(red[0] + red[1]);
    v.x *= rn; v.y *= rn; v.z *= rn; v.w *= rn;
    *(float4*)(dst + t * 4) = v;
}

// K4: tiled sim-GEMM + fused max/argmax. BM=BN=128, BK=32, 256 threads, 8x8 micro-tile.
__launch_bounds__(256)
__global__ void k_main(const float* __restrict__ s_n, const float* __restrict__ q_n,
                       unsigned long long* __restrict__ keys) {
    const int q0 = blockIdx.x * 128;
    const int s0 = blockIdx.y * 128;

    __shared__ float q_lds[32][128];
    __shared__ float s_lds[32][128];
    __shared__ unsigned long long kl[128];

    const int tid  = threadIdx.x;
    const int lane = tid & 63;
    const int w    = tid >> 6;        // wave 0..3
    const int wq   = w & 1;
    const int wsd  = w >> 1;
    const int qg   = lane & 7;
    const int sg   = lane >> 3;
    const int qb   = wq * 64 + qg * 8;   // query offset within tile (0..120)
    const int sb   = wsd * 64 + sg * 8;  // support offset within tile

    float acc[8][8];
    #pragma unroll
    for (int j = 0; j < 8; ++j)
        #pragma unroll
        for (int i = 0; i < 8; ++i) acc[j][i] = 0.0f;

    const int row = tid & 127;
    const int seg = tid >> 7;         // 0/1 -> which 16-col half of BK
    const int qrow = (q0 + row < NQRY) ? (q0 + row) : (NQRY - 1);
    const int srow = (s0 + row < NSUP) ? (s0 + row) : (NSUP - 1);
    const float* qsrc = q_n + (size_t)qrow * D + seg * 16;
    const float* ssrc = s_n + (size_t)srow * D + seg * 16;

    for (int kc = 0; kc < D; kc += 32) {
        __syncthreads();
        #pragma unroll
        for (int i4 = 0; i4 < 4; ++i4) {
            float4 a = *(const float4*)(qsrc + kc + i4 * 4);
            float4 b = *(const float4*)(ssrc + kc + i4 * 4);
            const int k0 = seg * 16 + i4 * 4;
            q_lds[k0 + 0][row] = a.x; q_lds[k0 + 1][row] = a.y;
            q_lds[k0 + 2][row] = a.z; q_lds[k0 + 3][row] = a.w;
            s_lds[k0 + 0][row] = b.x; s_lds[k0 + 1][row] = b.y;
            s_lds[k0 + 2][row] = b.z; s_lds[k0 + 3][row] = b.w;
        }
        __syncthreads();
        #pragma unroll 8
        for (int kk = 0; kk < 32; ++kk) {
            float4 a01 = *(const float4*)&q_lds[kk][qb];
            float4 a23 = *(const float4*)&q_lds[kk][qb + 4];
            float4 b01 = *(const float4*)&s_lds[kk][sb];
            float4 b23 = *(const float4*)&s_lds[kk][sb + 4];
            float av[8] = {a01.x, a01.y, a01.z, a01.w, a23.x, a23.y, a23.z, a23.w};
            float bv[8] = {b01.x, b01.y, b01.z, b01.w, b23.x, b23.y, b23.z, b23.w};
            #pragma unroll
            for (int j = 0; j < 8; ++j)
                #pragma unroll
                for (int i = 0; i < 8; ++i)
                    acc[j][i] = fmaf(av[j], bv[i], acc[j][i]);
        }
    }

    // ---- epilogue: fused max/argmax ----
    if (tid < 128) kl[tid] = 0ull;
    __syncthreads();
    #pragma unroll
    for (int j = 0; j < 8; ++j) {
        const int q = q0 + qb + j;
        if (q >= NQRY) continue;
        unsigned long long best = 0ull;
        #pragma unroll
        for (int i = 0; i < 8; ++i) {
            const int s = s0 + sb + i;
            if (s < NSUP) {
                unsigned long long k = pack_key(acc[j][i], s);
                if (k > best) best = k;
            }
        }
        if (best) atomicMax(&kl[qb + j], best);
    }
    __syncthreads();
    if (tid < 128) {
        const int q = q0 + tid;
        if (q < NQRY && kl[tid] != 0ull) atomicMax(&keys[q], kl[tid]);
    }
}

// K5: decode packed key -> class index
__global__ void k_decode(const unsigned long long* __restrict__ keys, int* __restrict__ out) {
    const int q = blockIdx.x * 256 + threadIdx.x;
    if (q < NQRY) {
        unsigned sidx = 0xFFFFFFFFu - (unsigned)(keys[q] & 0xFFFFFFFFull);
        out[q] = (int)(sidx / 5u);
    }
}

extern "C" void kernel_launch(void* const* d_in, const int* in_sizes, int n_in,
                              void* d_out, int out_size, void* d_ws, size_t ws_size,
                              hipStream_t stream) {
    const float* sup = (const float*)d_in[0];   // [1000,5,512] -> [5000][512]
    const float* qry = (const float*)d_in[1];   // [5000][512]
    // d_in[2] = use_cosine: irrelevant — after normalization, argmin-euclid == argmax-cosine.
    int* out = (int*)d_out;

    char* ws = (char*)d_ws;
    float* s_n     = (float*)(ws + OFF_SN);
    float* q_n     = (float*)(ws + OFF_QN);
    float* partial = (float*)(ws + OFF_PARTIAL);
    float* mean    = (float*)(ws + OFF_MEAN);
    unsigned long long* keys = (unsigned long long*)(ws + OFF_KEYS);

    k_partial_mean<<<MEAN_BLOCKS, 512, 0, stream>>>(sup, partial);
    k_mean_init<<<1, 512, 0, stream>>>(partial, mean, keys);
    k_normalize<<<NSUP + NQRY, 128, 0, stream>>>(sup, qry, mean, s_n, q_n);
    dim3 grid((NQRY + 127) / 128, (NSUP + 127) / 128);
    k_main<<<grid, 256, 0, stream>>>(s_n, q_n, keys);
    k_decode<<<(NQRY + 255) / 256, 256, 0, stream>>>(keys, out);
}

// Round 2
// 179.933 us; speedup vs baseline: 2.1896x; 2.1896x over previous
//
#include <hip/hip_runtime.h>
#include <stdint.h>

#define D     512
#define NSUP  5000   // 1000 classes * 5 shots
#define NQRY  5000
#define NPAD  5120   // 40 tiles of 128
#define MEAN_BLOCKS 100
#define ROWS_PER_MEAN_BLOCK 50
#define SCALE 512.0f

// ---------------- ws layout (bytes) ----------------
// shi  : [5120][512] f16 @ 0          (5,242,880)
// slo  : [5120][512] f16 @ 5,242,880
// qhi  : [5120][512] f16 @ 10,485,760
// qlo  : [5120][512] f16 @ 15,728,640
// partial : [100][512] f32 @ 20,971,520 (204,800)
// mean    : [512] f32      @ 21,176,320 (2,048)
// keys    : [5000] u64     @ 21,178,368 (40,000)   -> total 21,218,368 (same as R1)
#define OFF_SHI     0
#define OFF_SLO     5242880
#define OFF_QHI     10485760
#define OFF_QLO     15728640
#define OFF_PARTIAL 20971520
#define OFF_MEAN    21176320
#define OFF_KEYS    21178368

typedef _Float16 half4v __attribute__((ext_vector_type(4)));
typedef _Float16 half8v __attribute__((ext_vector_type(8)));
typedef float    f32x4  __attribute__((ext_vector_type(4)));

__device__ __forceinline__ unsigned long long pack_key(float v, int sidx) {
    unsigned u = __float_as_uint(v);
    u = (u & 0x80000000u) ? ~u : (u | 0x80000000u);   // monotone float->uint
    return ((unsigned long long)u << 32) | (unsigned)(0xFFFFFFFFu - (unsigned)sidx);
}

__device__ __forceinline__ void gload16(const void* g, void* l) {
    __builtin_amdgcn_global_load_lds(
        (const __attribute__((address_space(1))) unsigned int*)g,
        (__attribute__((address_space(3))) unsigned int*)l, 16, 0, 0);
}

// K1: partial column sums of support rows (deterministic 2-stage mean)
__global__ void k_partial_mean(const float* __restrict__ sup, float* __restrict__ partial) {
    const int col = threadIdx.x;           // 512
    const int b   = blockIdx.x;            // 100
    const int r0  = b * ROWS_PER_MEAN_BLOCK;
    float acc = 0.0f;
    for (int r = 0; r < ROWS_PER_MEAN_BLOCK; ++r)
        acc += sup[(size_t)(r0 + r) * D + col];
    partial[b * D + col] = acc;
}

// K2: finish mean, zero keys
__global__ void k_mean_init(const float* __restrict__ partial, float* __restrict__ mean,
                            unsigned long long* __restrict__ keys) {
    const int col = threadIdx.x;           // 512
    float acc = 0.0f;
    for (int b = 0; b < MEAN_BLOCKS; ++b) acc += partial[b * D + col];
    mean[col] = acc * (1.0f / (float)NSUP);
    for (int i = col; i < NSUP; i += 512) keys[i] = 0ull;
}

// K3: center + L2-normalize + scale by 512 + split into fp16 hi/lo.
// grid = 2*NPAD blocks x 128 threads; pad rows written as zeros.
__global__ void k_split(const float* __restrict__ sup, const float* __restrict__ qry,
                        const float* __restrict__ mean,
                        _Float16* __restrict__ shi, _Float16* __restrict__ slo,
                        _Float16* __restrict__ qhi, _Float16* __restrict__ qlo) {
    const int b = blockIdx.x;
    const int t = threadIdx.x;             // 128 threads x 4 floats
    const float* src; _Float16 *dhi, *dlo; int valid;
    if (b < NPAD) { src = sup + (size_t)b * D;
                    dhi = shi + (size_t)b * D; dlo = slo + (size_t)b * D; valid = (b < NSUP); }
    else        { int r = b - NPAD; src = qry + (size_t)r * D;
                    dhi = qhi + (size_t)r * D; dlo = qlo + (size_t)r * D; valid = (r < NQRY); }
    if (!valid) {
        half4v z = {};
        *(half4v*)(dhi + t * 4) = z;
        *(half4v*)(dlo + t * 4) = z;
        return;
    }
    float4 v = *(const float4*)(src + t * 4);
    float4 m = *(const float4*)(mean + t * 4);
    v.x -= m.x; v.y -= m.y; v.z -= m.z; v.w -= m.w;
    float ss = v.x * v.x + v.y * v.y + v.z * v.z + v.w * v.w;
    #pragma unroll
    for (int off = 32; off > 0; off >>= 1) ss += __shfl_down(ss, off, 64);
    __shared__ float red[2];
    if ((t & 63) == 0) red[t >> 6] = ss;
    __syncthreads();
    const float rn = SCALE / sqrtf(red[0] + red[1]);
    float sv[4] = {v.x * rn, v.y * rn, v.z * rn, v.w * rn};
    half4v h, l;
    #pragma unroll
    for (int i = 0; i < 4; ++i) {
        _Float16 hh = (_Float16)sv[i];
        h[i] = hh;
        l[i] = (_Float16)(sv[i] - (float)hh);
    }
    *(half4v*)(dhi + t * 4) = h;
    *(half4v*)(dlo + t * 4) = l;
}

// K4: MFMA sim-GEMM (3-term fp16-split) + fused max/argmax.
// 128x128 tile, BK=32, 256 threads, wave tile 64x64 (4x4 frags of 16x16x32).
__launch_bounds__(256)
__global__ void k_main(const _Float16* __restrict__ shi, const _Float16* __restrict__ slo,
                       const _Float16* __restrict__ qhi, const _Float16* __restrict__ qlo,
                       unsigned long long* __restrict__ keys) {
    __shared__ __align__(16) _Float16 lds_shi[128 * 32];
    __shared__ __align__(16) _Float16 lds_slo[128 * 32];
    __shared__ __align__(16) _Float16 lds_qhi[128 * 32];
    __shared__ __align__(16) _Float16 lds_qlo[128 * 32];
    __shared__ unsigned long long kl[128];

    const int tid  = threadIdx.x;
    const int lane = tid & 63;
    const int wv   = tid >> 6;            // 4 waves
    const int q0   = blockIdx.x * 128;
    const int s0   = blockIdx.y * 128;

    // ---- staging address precompute (swizzle: slot ^= (row>>1)&3, 16B slots) ----
    // dest offset within tile (linear, what global_load_lds writes): wv*2048 + j*1024 + lane*16
    const int m0  = wv * 32 + (lane >> 2);       // row for j=0 chunk
    const int m1  = m0 + 16;                     // row for j=1 chunk
    const int sl0 = ((lane & 3) ^ ((m0 >> 1) & 3)) * 16;
    const int sl1 = ((lane & 3) ^ ((m1 >> 1) & 3)) * 16;
    const char* pShi = (const char*)shi; const char* pSlo = (const char*)slo;
    const char* pQhi = (const char*)qhi; const char* pQlo = (const char*)qlo;
    const size_t rS0 = (size_t)(s0 + m0) * 1024 + sl0;
    const size_t rS1 = (size_t)(s0 + m1) * 1024 + sl1;
    const size_t rQ0 = (size_t)(q0 + m0) * 1024 + sl0;
    const size_t rQ1 = (size_t)(q0 + m1) * 1024 + sl1;
    _Float16* dj0 = (_Float16*)0; // silence
    _Float16* d_shi0 = lds_shi + wv * 1024;      _Float16* d_shi1 = lds_shi + wv * 1024 + 512;
    _Float16* d_slo0 = lds_slo + wv * 1024;      _Float16* d_slo1 = lds_slo + wv * 1024 + 512;
    _Float16* d_qhi0 = lds_qhi + wv * 1024;      _Float16* d_qhi1 = lds_qhi + wv * 1024 + 512;
    _Float16* d_qlo0 = lds_qlo + wv * 1024;      _Float16* d_qlo1 = lds_qlo + wv * 1024 + 512;
    (void)dj0;

    // ---- fragment read addresses (same swizzle) ----
    const int l15 = lane & 15;
    const int kg  = lane >> 4;                   // k-group 0..3
    const int fo  = l15 * 64 + ((kg ^ ((l15 >> 1) & 3)) * 16);  // per-lane byte offset
    const int sm  = (wv & 1) * 64;               // support row base in tile
    const int qm  = (wv >> 1) * 64;              // query row base in tile
    const char* fShi = (const char*)lds_shi + (size_t)sm * 64 + fo;
    const char* fSlo = (const char*)lds_slo + (size_t)sm * 64 + fo;
    const char* fQhi = (const char*)lds_qhi + (size_t)qm * 64 + fo;
    const char* fQlo = (const char*)lds_qlo + (size_t)qm * 64 + fo;

    f32x4 acc[4][4] = {};
    if (tid < 128) kl[tid] = 0ull;

    for (int kc = 0; kc < D; kc += 32) {
        const size_t kb = (size_t)kc * 2;        // byte offset along K
        __syncthreads();                         // prev-iter LDS reads complete
        gload16(pShi + rS0 + kb, d_shi0);  gload16(pShi + rS1 + kb, d_shi1);
        gload16(pSlo + rS0 + kb, d_slo0);  gload16(pSlo + rS1 + kb, d_slo1);
        gload16(pQhi + rQ0 + kb, d_qhi0);  gload16(pQhi + rQ1 + kb, d_qhi1);
        gload16(pQlo + rQ0 + kb, d_qlo0);  gload16(pQlo + rQ1 + kb, d_qlo1);
        __syncthreads();                         // compiler drains vmcnt before barrier

        half8v ah[4], al[4], bh[4], bl[4];
        #pragma unroll
        for (int f = 0; f < 4; ++f) {
            ah[f] = *(const half8v*)(fShi + f * 1024);
            al[f] = *(const half8v*)(fSlo + f * 1024);
            bh[f] = *(const half8v*)(fQhi + f * 1024);
            bl[f] = *(const half8v*)(fQlo + f * 1024);
        }
        #pragma unroll
        for (int fa = 0; fa < 4; ++fa)
            #pragma unroll
            for (int fb = 0; fb < 4; ++fb) {
                acc[fa][fb] = __builtin_amdgcn_mfma_f32_16x16x32_f16(ah[fa], bh[fb], acc[fa][fb], 0, 0, 0);
                acc[fa][fb] = __builtin_amdgcn_mfma_f32_16x16x32_f16(ah[fa], bl[fb], acc[fa][fb], 0, 0, 0);
                acc[fa][fb] = __builtin_amdgcn_mfma_f32_16x16x32_f16(al[fa], bh[fb], acc[fa][fb], 0, 0, 0);
            }
    }

    // ---- fused argmax epilogue ----
    // C/D: col(query) = lane&15 (+fb*16+qm), row(support) = kg*4 + r (+fa*16+sm)
    __syncthreads();
    #pragma unroll
    for (int fb = 0; fb < 4; ++fb) {
        unsigned long long best = 0ull;
        #pragma unroll
        for (int fa = 0; fa < 4; ++fa)
            #pragma unroll
            for (int r = 0; r < 4; ++r) {
                const int s = s0 + sm + fa * 16 + kg * 4 + r;
                if (s < NSUP) {
                    unsigned long long k = pack_key(acc[fa][fb][r], s);
                    if (k > best) best = k;
                }
            }
        unsigned long long o = __shfl_xor(best, 16, 64); if (o > best) best = o;
        o = __shfl_xor(best, 32, 64);                    if (o > best) best = o;
        if (kg == 0) atomicMax(&kl[qm + fb * 16 + l15], best);
    }
    __syncthreads();
    if (tid < 128) {
        const int q = q0 + tid;
        if (q < NQRY && kl[tid] != 0ull) atomicMax(&keys[q], kl[tid]);
    }
}

// K5: decode packed key -> class index
__global__ void k_decode(const unsigned long long* __restrict__ keys, int* __restrict__ out) {
    const int q = blockIdx.x * 256 + threadIdx.x;
    if (q < NQRY) {
        unsigned sidx = 0xFFFFFFFFu - (unsigned)(keys[q] & 0xFFFFFFFFull);
        out[q] = (int)(sidx / 5u);
    }
}

extern "C" void kernel_launch(void* const* d_in, const int* in_sizes, int n_in,
                              void* d_out, int out_size, void* d_ws, size_t ws_size,
                              hipStream_t stream) {
    const float* sup = (const float*)d_in[0];   // [1000,5,512]
    const float* qry = (const float*)d_in[1];   // [5000,512]
    // d_in[2] = use_cosine: after normalization argmin-euclid == argmax-cosine.
    int* out = (int*)d_out;

    char* ws = (char*)d_ws;
    _Float16* shi = (_Float16*)(ws + OFF_SHI);
    _Float16* slo = (_Float16*)(ws + OFF_SLO);
    _Float16* qhi = (_Float16*)(ws + OFF_QHI);
    _Float16* qlo = (_Float16*)(ws + OFF_QLO);
    float* partial = (float*)(ws + OFF_PARTIAL);
    float* mean    = (float*)(ws + OFF_MEAN);
    unsigned long long* keys = (unsigned long long*)(ws + OFF_KEYS);

    k_partial_mean<<<MEAN_BLOCKS, 512, 0, stream>>>(sup, partial);
    k_mean_init<<<1, 512, 0, stream>>>(partial, mean, keys);
    k_split<<<2 * NPAD, 128, 0, stream>>>(sup, qry, mean, shi, slo, qhi, qlo);
    dim3 grid(NPAD / 128, NPAD / 128);
    k_main<<<grid, 256, 0, stream>>>(shi, slo, qhi, qlo, keys);
    k_decode<<<(NQRY + 255) / 256, 256, 0, stream>>>(keys, out);
}